// Round 2
// baseline (269.023 us; speedup 1.0000x reference)
//
#include <hip/hip_runtime.h>
#include <hip/hip_bf16.h>

// Fused Interaction Estimator, v2: persistent-W-in-registers.
// 512 blocks x 512 threads (8 waves). Each wave owns a 32-col slice of the
// output; W fragments for BOTH branches live in registers (128 VGPRs),
// loaded once per block and reused across 6 row-tiles of 32 rows.
// Inner loop is pure LDS ds_read_b128 + MFMA; A staging (f32->bf16 +
// XOR-swizzled LDS write) is issued early to overlap compute.

typedef float f32x4 __attribute__((ext_vector_type(4)));
typedef short short8 __attribute__((ext_vector_type(8)));

#define D_DIM 256
#define ROWS 32
#define NW 8
#define NBLOCKS 512

__device__ __forceinline__ unsigned short f2bf(float x) {
  unsigned int u = __float_as_uint(x);
  unsigned int r = (u + 0x7FFFu + ((u >> 16) & 1u)) >> 16;
  return (unsigned short)r;
}

__device__ __forceinline__ float sigm(float x) {
  return 1.0f / (1.0f + __expf(-x));
}

// ---------------- prep: pack W (f32 [k][m] row-major) into bf16 MFMA B-fragment order ----
// chunk = (c*8 + t)*64 + l holds 8 bf16: B[k = t*32 + (l>>4)*8 + j][m = c*16 + (l&15)]
__global__ __launch_bounds__(256) void pack_w_kernel(const float* __restrict__ Wg,
                                                     const float* __restrict__ Wp,
                                                     unsigned short* __restrict__ outp) {
  int b = blockIdx.x;
  const float* W = (b < 32) ? Wg : Wp;
  unsigned short* o = outp + (b < 32 ? 0 : 65536);
  int chunk = (b & 31) * 256 + threadIdx.x;
  int c = chunk >> 9;
  int rest = chunk & 511;
  int t = rest >> 6;
  int l = rest & 63;
  int m = c * 16 + (l & 15);
  int kb = t * 32 + ((l >> 4) << 3);
  short8 v;
#pragma unroll
  for (int j = 0; j < 8; ++j) v[j] = (short)f2bf(W[(kb + j) * 256 + m]);
  *(short8*)(o + (size_t)chunk * 8) = v;
}

// ---------------- main fused kernel ----------------

__device__ __forceinline__ short8 readA(const unsigned short* smA, int rt, int t, int lane) {
  int row = rt * 16 + (lane & 15);
  int off = (row * 512 + t * 64 + ((lane >> 4) << 4)) ^ ((row & 7) << 4);
  return *(const short8*)((const char*)smA + off);
}

// 512 threads stage one 32x256 f32 tile as swizzled bf16 (4 float4 per thread)
__device__ __forceinline__ void stageA(const float* __restrict__ src, unsigned short* smA, int tid) {
  const float4* s4 = (const float4*)src;
#pragma unroll
  for (int it = 0; it < 4; ++it) {
    int idx = it * 512 + tid;
    int row = idx >> 6;
    int k4 = (idx & 63) << 2;
    float4 v = s4[idx];
    ushort4 h;
    h.x = f2bf(v.x); h.y = f2bf(v.y); h.z = f2bf(v.z); h.w = f2bf(v.w);
    int off = (row * 512 + k4 * 2) ^ ((row & 7) << 4);
    *(ushort4*)((char*)smA + off) = h;
  }
}

__device__ __forceinline__ void gemm2(f32x4 acc[2][2], const unsigned short* smA,
                                      const short8 wf[2][8], int lane) {
#pragma unroll
  for (int t = 0; t < 8; ++t) {
    short8 a0 = readA(smA, 0, t, lane);
    short8 a1 = readA(smA, 1, t, lane);
#pragma unroll
    for (int c = 0; c < 2; ++c) {
      acc[0][c] = __builtin_amdgcn_mfma_f32_16x16x32_bf16(a0, wf[c][t], acc[0][c], 0, 0, 0);
      acc[1][c] = __builtin_amdgcn_mfma_f32_16x16x32_bf16(a1, wf[c][t], acc[1][c], 0, 0, 0);
    }
  }
}

__device__ __forceinline__ void statsPhase(f32x4 acc[2][2], const float* __restrict__ bias,
                                           float smSum[NW][32], float smSq[NW][32],
                                           int lane, int w) {
  float bv[2];
#pragma unroll
  for (int c = 0; c < 2; ++c) bv[c] = bias[w * 32 + c * 16 + (lane & 15)];
#pragma unroll
  for (int rt = 0; rt < 2; ++rt) {
#pragma unroll
    for (int r = 0; r < 4; ++r) {
      float s = 0.f, qq = 0.f;
#pragma unroll
      for (int c = 0; c < 2; ++c) {
        float y = acc[rt][c][r] + bv[c];
        acc[rt][c][r] = y;
        s += y; qq += y * y;
      }
#pragma unroll
      for (int m = 1; m < 16; m <<= 1) {
        s += __shfl_xor(s, m, 64);
        qq += __shfl_xor(qq, m, 64);
      }
      if ((lane & 15) == 0) {
        int row = rt * 16 + ((lane >> 4) << 2) + r;
        smSum[w][row] = s;
        smSq[w][row] = qq;
      }
    }
  }
}

__device__ __forceinline__ void applyPhase(f32x4 acc[2][2], f32x4 outAl[2][2],
                                           const float* __restrict__ gam, const float* __restrict__ bet,
                                           const float* __restrict__ wa,
                                           const float smSum[NW][32], const float smSq[NW][32],
                                           float smRed[NW][32], int lane, int w) {
  int cb = w * 32 + (lane & 15);
  float gv[2], tv[2], wv[2];
#pragma unroll
  for (int c = 0; c < 2; ++c) {
    gv[c] = gam[cb + c * 16];
    tv[c] = bet[cb + c * 16];
    wv[c] = wa[cb + c * 16];
  }
#pragma unroll
  for (int rt = 0; rt < 2; ++rt) {
#pragma unroll
    for (int r = 0; r < 4; ++r) {
      int row = rt * 16 + ((lane >> 4) << 2) + r;
      float s = 0.f, qq = 0.f;
#pragma unroll
      for (int k = 0; k < NW; ++k) { s += smSum[k][row]; qq += smSq[k][row]; }
      float mu = s * (1.0f / 256.0f);
      float var = qq * (1.0f / 256.0f) - mu * mu;
      var = fmaxf(var, 0.0f);
      float rs = rsqrtf(var + 1e-5f);
      float dp = 0.f;
#pragma unroll
      for (int c = 0; c < 2; ++c) {
        float a = (acc[rt][c][r] - mu) * rs * gv[c] + tv[c];
        a = fmaxf(a, 0.0f);
        outAl[rt][c][r] = a;
        dp += a * wv[c];
      }
#pragma unroll
      for (int m = 1; m < 16; m <<= 1) dp += __shfl_xor(dp, m, 64);
      if ((lane & 15) == 0) smRed[w][row] = dp;
    }
  }
}

__global__ __launch_bounds__(512, 2) void fused_main(
    const float* __restrict__ gfeat, const float* __restrict__ pfeat,
    const float* __restrict__ bg, const float* __restrict__ glng, const float* __restrict__ glnb,
    const float* __restrict__ bp, const float* __restrict__ plng, const float* __restrict__ plnb,
    const float* __restrict__ wag, const float* __restrict__ bag,
    const float* __restrict__ wap, const float* __restrict__ bap,
    const unsigned short* __restrict__ wpk,
    float* __restrict__ outp, int tilesPerBlock)
{
  __shared__ unsigned short bufA[2][ROWS * D_DIM];   // 2 x 16 KB
  __shared__ float smSum[NW][32];
  __shared__ float smSq[NW][32];
  __shared__ float smRedG[NW][32];
  __shared__ float smRedP[NW][32];

  const int tid = threadIdx.x;
  const int lane = tid & 63;
  const int w = tid >> 6;

  const int tile0 = blockIdx.x * tilesPerBlock;
  const float* gsrc = gfeat + (size_t)tile0 * ROWS * D_DIM;
  const float* psrc = pfeat + (size_t)tile0 * ROWS * D_DIM;
  float* obase = outp + (size_t)tile0 * ROWS * D_DIM;

  // stage first g tile, then load persistent W fragments (both overlap), then sync
  stageA(gsrc, bufA[0], tid);

  short8 wfg[2][8], wfp[2][8];
  {
    const short8* wp8 = (const short8*)wpk;
#pragma unroll
    for (int c = 0; c < 2; ++c)
#pragma unroll
      for (int t = 0; t < 8; ++t) {
        int idx = (((w * 2 + c) * 8 + t) << 6) + lane;
        wfg[c][t] = wp8[idx];
        wfp[c][t] = wp8[8192 + idx];
      }
  }
  __syncthreads();

  const float vbag = bag[0], vbap = bap[0];

  for (int i = 0; i < tilesPerBlock; ++i) {
    const size_t tb = (size_t)i * ROWS * D_DIM;

    // issue p(i) staging early; overlaps g gemm
    stageA(psrc + tb, bufA[1], tid);

    f32x4 accG[2][2];
#pragma unroll
    for (int rt = 0; rt < 2; ++rt)
#pragma unroll
      for (int c = 0; c < 2; ++c) accG[rt][c] = {0.f, 0.f, 0.f, 0.f};
    gemm2(accG, bufA[0], wfg, lane);
    statsPhase(accG, bg, smSum, smSq, lane, w);
    __syncthreads();   // #1: statsG visible; p(i) staged; bufA[0] reads done

    f32x4 alignG[2][2];
    applyPhase(accG, alignG, glng, glnb, wap, smSum, smSq, smRedG, lane, w);

    if (i + 1 < tilesPerBlock)
      stageA(gsrc + tb + ROWS * D_DIM, bufA[0], tid);   // g(i+1)

    f32x4 accP[2][2];
#pragma unroll
    for (int rt = 0; rt < 2; ++rt)
#pragma unroll
      for (int c = 0; c < 2; ++c) accP[rt][c] = {0.f, 0.f, 0.f, 0.f};
    gemm2(accP, bufA[1], wfp, lane);
    __syncthreads();   // #2: applyG's smSum reads done; smRedG visible; bufA[1] reads done

    statsPhase(accP, bp, smSum, smSq, lane, w);
    __syncthreads();   // #3: statsP visible

    applyPhase(accP, accP, plng, plnb, wag, smSum, smSq, smRedP, lane, w);
    __syncthreads();   // #4: smRedP visible; applyP's smSum reads done

    // fusion + store
#pragma unroll
    for (int rt = 0; rt < 2; ++rt) {
#pragma unroll
      for (int r = 0; r < 4; ++r) {
        int row = rt * 16 + ((lane >> 4) << 2) + r;
        float gr = 0.f, pr = 0.f;
#pragma unroll
        for (int k = 0; k < NW; ++k) { gr += smRedG[k][row]; pr += smRedP[k][row]; }
        float* orow = obase + tb + (size_t)row * D_DIM + w * 32 + (lane & 15);
#pragma unroll
        for (int c = 0; c < 2; ++c) {
          float ga = alignG[rt][c][r];
          float pa = accP[rt][c][r];
          float geno = sigm(ga * pr + vbag);
          float path = sigm(pa * gr + vbap);
          orow[c * 16] = pa * path + ga * geno;
        }
      }
    }
    // no barrier needed before next iteration:
    //  - statsG(i+1) writes smSum only after sync #4 (program order)        [safe]
    //  - fusion reads smRedG/P happen before sync #1 of iter i+1, the
    //    earliest point any wave can rewrite them                            [safe]
    //  - bufA[1] rewrite (stage p(i+1)) is after all gemm_p reads (< #2)     [safe]
  }
}

extern "C" void kernel_launch(void* const* d_in, const int* in_sizes, int n_in,
                              void* d_out, int out_size, void* d_ws, size_t ws_size,
                              hipStream_t stream) {
  const float* gfeat = (const float*)d_in[0];
  const float* pfeat = (const float*)d_in[1];
  const float* Wg   = (const float*)d_in[2];
  const float* bg   = (const float*)d_in[3];
  const float* glng = (const float*)d_in[4];
  const float* glnb = (const float*)d_in[5];
  const float* Wp   = (const float*)d_in[6];
  const float* bp   = (const float*)d_in[7];
  const float* plng = (const float*)d_in[8];
  const float* plnb = (const float*)d_in[9];
  const float* wag  = (const float*)d_in[10];
  const float* bag  = (const float*)d_in[11];
  const float* wap  = (const float*)d_in[12];
  const float* bap  = (const float*)d_in[13];
  float* outp = (float*)d_out;
  unsigned short* wpk = (unsigned short*)d_ws;

  hipLaunchKernelGGL(pack_w_kernel, dim3(64), dim3(256), 0, stream, Wg, Wp, wpk);

  int nrows = in_sizes[0] / D_DIM;          // 98304
  int tiles = nrows / ROWS;                 // 3072
  int tilesPerBlock = tiles / NBLOCKS;      // 6
  hipLaunchKernelGGL(fused_main, dim3(NBLOCKS), dim3(512), 0, stream,
                     gfeat, pfeat, bg, glng, glnb, bp, plng, plnb,
                     wag, bag, wap, bap, wpk, outp, tilesPerBlock);
}